// Round 11
// baseline (28.317 us; speedup 1.0000x reference)
//
#include <hip/hip_runtime.h>
#include <math.h>

constexpr int NXc = 256, NYc = 256, ETLc = 16, NTc = 100, NBc = 30;
constexpr int NPIX = NXc * NYc;
constexpr int TCHUNK = 13;          // T2 atoms per block
constexpr int NCHUNK = 8;           // 8*13 = 104 slots, 100 real
constexpr int RSTRIDE = 20;         // LDS row stride in floats: 8 consecutive rows tile all 32 banks

// ws layout: ws_f1[100*256] float (t-major, fully rewritten), ws_f2[256] float

__global__ __launch_bounds__(256) void k_main(
    const float* __restrict__ sig,      // [NPIX][16]
    const float* __restrict__ db_mag,   // [100][30][16]
    const float* __restrict__ dtt,      // [16]
    const float* __restrict__ est,      // [2][NPIX]
    float* __restrict__ ws_f1,          // [100][256] t-major
    float* __restrict__ ws_f2)          // [256]
{
    const int tid    = threadIdx.x;
    const int pixblk = blockIdx.x & 255;
    const int tchunk = blockIdx.x >> 8;   // 0..7
    const int p = (pixblk << 8) | tid;
    const int x = p >> 8;
    const int y = p & 255;
    const int t0 = tchunk * TCHUNK;
    const int wid = tid >> 6, lane = tid & 63;

    alignas(16) __shared__ float lds[TCHUNK * NBc * RSTRIDE];  // 31.2 KB
    __shared__ float s_part[TCHUNK * 4];
    __shared__ float s_f2[4];
    __shared__ int s_hist[NBc];
    __shared__ int s_base[NBc];
    __shared__ unsigned char s_ord[256];

    if (tid < NBc) s_hist[tid] = 0;

    // --- stage db slab [tcnt][30][16] -> LDS rows of RSTRIDE floats ---
    const int tcnt = (NTc - t0 < TCHUNK) ? (NTc - t0) : TCHUNK;
    const int nf4  = tcnt * 120;                       // float4s in slab
    const float4* gsrc = reinterpret_cast<const float4*>(db_mag + (size_t)t0 * (NBc * ETLc));
    for (int i = tid; i < nf4; i += 256) {
        const int ttl = i / 120;
        const int rem = i - ttl * 120;
        const int jbl = rem >> 2;
        const int k   = rem & 3;
        float4 v = gsrc[i];
        *reinterpret_cast<float4*>(&lds[ttl * (NBc * RSTRIDE) + jbl * RSTRIDE + k * 4]) = v;
    }

    // --- own-pixel jb (for the sort key) ---
    const float est1_own = est[NPIX + p];
    float kfo = roundf(est1_own * 29.0f);
    kfo = fminf(fmaxf(kfo, 0.0f), 29.0f);
    const int jb_own = (int)kfo;

    __syncthreads();                       // [A] hist zero visible
    atomicAdd(&s_hist[jb_own], 1);

    // --- f2 (TV of b1) on ORIGINAL pixel mapping — overlaps hist ---
    float f2r = 0.f;
    if (tchunk == 0) {
        const float* e1 = est + NPIX;
        const float c = 0.2f + 1.4f * est1_own;
        float g0, g1;
        if (x == 0)            g0 = (0.2f + 1.4f * e1[p + 256]) - c;
        else if (x == NXc - 1) g0 = c - (0.2f + 1.4f * e1[p - 256]);
        else                   g0 = 0.5f * ((0.2f + 1.4f * e1[p + 256]) - (0.2f + 1.4f * e1[p - 256]));
        if (y == 0)            g1 = (0.2f + 1.4f * e1[p + 1]) - c;
        else if (y == NYc - 1) g1 = c - (0.2f + 1.4f * e1[p - 1]);
        else                   g1 = 0.5f * ((0.2f + 1.4f * e1[p + 1]) - (0.2f + 1.4f * e1[p - 1]));
        f2r = fabsf(g0) + fabsf(g1);
#pragma unroll
        for (int m = 32; m; m >>= 1) f2r += __shfl_xor(f2r, m, 64);
        if (lane == 0) s_f2[wid] = f2r;
    }

    __syncthreads();                       // [B] hist + s_f2 complete
    if (tid == 0) {
        int a = 0;
#pragma unroll
        for (int j = 0; j < NBc; ++j) { s_base[j] = a; a += s_hist[j]; }
        if (tchunk == 0) ws_f2[pixblk] = s_f2[0] + s_f2[1] + s_f2[2] + s_f2[3];
    }
    __syncthreads();                       // [C] bases ready
    {
        const int rank = atomicAdd(&s_base[jb_own], 1);
        s_ord[rank] = (unsigned char)tid;
    }
    __syncthreads();                       // [D] sort + staging complete

    // --- work on the jb-sorted pixel ---
    const int q = (pixblk << 8) | (int)s_ord[tid];

    const float4* sp = reinterpret_cast<const float4*>(sig + (size_t)q * ETLc);
    float s[16];
    {
        float4 a = sp[0], b = sp[1], c = sp[2], d = sp[3];
        s[0]=a.x; s[1]=a.y; s[2]=a.z;  s[3]=a.w;
        s[4]=b.x; s[5]=b.y; s[6]=b.z;  s[7]=b.w;
        s[8]=c.x; s[9]=c.y; s[10]=c.z; s[11]=c.w;
        s[12]=d.x; s[13]=d.y; s[14]=d.z; s[15]=d.w;
    }
    float snrm2 = 0.f;
#pragma unroll
    for (int e = 0; e < 16; ++e) snrm2 = fmaf(s[e], s[e], snrm2);
    const float sig2  = (snrm2 > 0.f) ? 1.0f : 0.0f;
    const float srinv = (snrm2 > 0.f) ? __builtin_amdgcn_rsqf(snrm2) : 0.0f;
    float sgn[16];
#pragma unroll
    for (int e = 0; e < 16; ++e) sgn[e] = s[e] * srinv;

    const float est0 = est[q];
    const float t2p  = 1.0f + 499.0f * est0;
    const float nrcp = -__builtin_amdgcn_rcpf(t2p);
    float eta[16];
#pragma unroll
    for (int e = 0; e < 16; ++e) eta[e] = __expf(dtt[e] * nrcp);

    const float est1 = est[NPIX + q];
    float kf = roundf(est1 * 29.0f);
    kf = fminf(fmaxf(kf, 0.0f), 29.0f);
    const int jb = (int)kf;

    // --- main loop: sorted jb -> LDS reads broadcast/conflict-free ---
#pragma unroll 2
    for (int tt = 0; tt < TCHUNK; ++tt) {
        float r = 0.f;
        if (t0 + tt < NTc) {
            const float4* lp = reinterpret_cast<const float4*>(
                &lds[tt * (NBc * RSTRIDE) + jb * RSTRIDE]);
            float4 a = lp[0], b = lp[1], c = lp[2], d = lp[3];
            float dbr[16];
            dbr[0]=a.x; dbr[1]=a.y; dbr[2]=a.z;  dbr[3]=a.w;
            dbr[4]=b.x; dbr[5]=b.y; dbr[6]=b.z;  dbr[7]=b.w;
            dbr[8]=c.x; dbr[9]=c.y; dbr[10]=c.z; dbr[11]=c.w;
            dbr[12]=d.x; dbr[13]=d.y; dbr[14]=d.z; dbr[15]=d.w;

            float nrm2 = 0.f, dotv = 0.f;
#pragma unroll
            for (int e = 0; e < 16; ++e) {
                float v = dbr[e] * eta[e];
                nrm2 = fmaf(v, v, nrm2);
                dotv = fmaf(v, sgn[e], dotv);
            }
            float l2sq;
            if (nrm2 > 0.f) l2sq = sig2 + 1.0f - 2.0f * dotv * __builtin_amdgcn_rsqf(nrm2);
            else            l2sq = sig2;
            r = (l2sq < 0.f) ? 0.f : l2sq;
        }
#pragma unroll
        for (int m = 32; m; m >>= 1) r += __shfl_xor(r, m, 64);
        if (lane == 0) s_part[tt * 4 + wid] = r;
    }
    __syncthreads();
    if (tid < TCHUNK && t0 + tid < NTc) {
        float bsum = s_part[tid*4+0] + s_part[tid*4+1] + s_part[tid*4+2] + s_part[tid*4+3];
        ws_f1[(size_t)(t0 + tid) * 256 + pixblk] = bsum;   // t-major
    }
}

__global__ __launch_bounds__(512) void k_final(
    const float* __restrict__ ws_f1,   // [100][256] t-major
    const float* __restrict__ ws_f2,   // [256]
    float* __restrict__ out)
{
    const int tid = threadIdx.x;       // 512 threads: (t = tid>>2) x (g = tid&3)
    const int t = tid >> 2, g = tid & 3;
    float sum = 0.f;
    if (t < NTc) {
        const float4* p4 = reinterpret_cast<const float4*>(ws_f1 + (size_t)t * 256 + g * 64);
#pragma unroll
        for (int i = 0; i < 16; ++i) { float4 v = p4[i]; sum += (v.x + v.y) + (v.z + v.w); }
    }
    sum += __shfl_xor(sum, 1, 64);
    sum += __shfl_xor(sum, 2, 64);

    __shared__ float s_sq[128];
    if (tid < 128) s_sq[tid] = 0.f;
    __syncthreads();
    if (g == 0 && t < NTc) s_sq[t] = sqrtf(sum);
    __syncthreads();

    if (tid < 64) {
        float v = s_sq[tid] + s_sq[tid + 64];
        v += (ws_f2[tid] + ws_f2[tid + 64]) + (ws_f2[tid + 128] + ws_f2[tid + 192]);
#pragma unroll
        for (int m = 32; m; m >>= 1) v += __shfl_xor(v, m, 64);
        if (tid == 0) out[0] = v;
    }
}

extern "C" void kernel_launch(void* const* d_in, const int* in_sizes, int n_in,
                              void* d_out, int out_size, void* d_ws, size_t ws_size,
                              hipStream_t stream) {
    const float* sig    = (const float*)d_in[0];  // slice_signal (256,256,16)
    const float* db_mag = (const float*)d_in[1];  // (100,30,16)
    // d_in[2] = db_t2s_ms — unused by the reference
    // d_in[3] = db_b1s — replaced by analytic linspace index
    const float* dtt    = (const float*)d_in[4];  // (16,)
    const float* est    = (const float*)d_in[5];  // (2,256,256)
    float* out = (float*)d_out;

    float* ws_f1 = (float*)d_ws;                  // [100][256] t-major
    float* ws_f2 = ws_f1 + (size_t)NTc * 256;     // [256]

    k_main <<<dim3(256 * NCHUNK), dim3(256), 0, stream>>>(sig, db_mag, dtt, est, ws_f1, ws_f2);
    k_final<<<dim3(1),            dim3(512), 0, stream>>>(ws_f1, ws_f2, out);
}